// Round 1
// baseline (591.491 us; speedup 1.0000x reference)
//
#include <hip/hip_runtime.h>

#define N_NODES 100000
#define N_EDGES 1200000
#define D 64
#define KEEP_PROB 0.7f

// ---------------------------------------------------------------------------
// zero x1 buffer (float4)
__global__ __launch_bounds__(256) void zero_kernel(float4* __restrict__ p, int n4) {
    int i = blockIdx.x * 256 + threadIdx.x;
    if (i < n4) p[i] = make_float4(0.f, 0.f, 0.f, 0.f);
}

// ---------------------------------------------------------------------------
// SpMM scatter: one wave per edge, one lane per feature.
// x_out[rows[e]*D + lane] += (vals[e]/KEEP_PROB) * x_in[cols[e]*D + lane]
// for kept edges: (u + KEEP_PROB) >= 1.0
__global__ __launch_bounds__(256) void spmm_kernel(
    const float* __restrict__ x_in,
    const float* __restrict__ vals,
    const float* __restrict__ drop_u,   // pre-offset for the layer
    const int*   __restrict__ rows,
    const int*   __restrict__ cols,
    float*       __restrict__ x_out) {
    int wave = (blockIdx.x * 256 + threadIdx.x) >> 6;
    int lane = threadIdx.x & 63;
    if (wave >= N_EDGES) return;
    float u = drop_u[wave];
    if (u + KEEP_PROB < 1.0f) return;       // dropped edge
    float v = vals[wave] / KEEP_PROB;
    int r = rows[wave];
    int c = cols[wave];
    float x = x_in[c * D + lane];
    atomicAdd(&x_out[r * D + lane], v * x);
}

// ---------------------------------------------------------------------------
// out[n,j] = b[j] + sum_k emb[n,k]*W[j,k] + x1[n,j]
// 4 nodes per 256-thread block; W staged in LDS (padded stride 65).
__global__ __launch_bounds__(256) void fc_add_kernel(
    const float* __restrict__ emb,
    const float* __restrict__ W,
    const float* __restrict__ b,
    const float* __restrict__ x1,
    float*       __restrict__ out) {
    __shared__ float Ws[D * 65];   // [j][k] at j*65+k  (pad breaks 64-stride conflicts)
    __shared__ float Es[4 * D];

    int t = threadIdx.x;
    // stage W: 4096 floats, coalesced
    #pragma unroll
    for (int i = 0; i < 16; ++i) {
        int idx = i * 256 + t;
        Ws[(idx >> 6) * 65 + (idx & 63)] = W[idx];
    }
    int node0 = blockIdx.x * 4;
    // stage 4 emb rows: contiguous 256 floats
    Es[t] = emb[node0 * D + t];
    __syncthreads();

    int local = t >> 6;
    int j     = t & 63;
    int n     = node0 + local;

    float acc = b[j];
    const float* es = &Es[local * D];
    const float* ws = &Ws[j * 65];
    #pragma unroll
    for (int k = 0; k < D; ++k) acc += es[k] * ws[k];
    out[n * D + j] = acc + x1[n * D + j];
}

// ---------------------------------------------------------------------------
// out *= 1/3
__global__ __launch_bounds__(256) void scale_kernel(float4* __restrict__ p, int n4) {
    int i = blockIdx.x * 256 + threadIdx.x;
    if (i < n4) {
        float4 v = p[i];
        v.x /= 3.0f; v.y /= 3.0f; v.z /= 3.0f; v.w /= 3.0f;
        p[i] = v;
    }
}

// ---------------------------------------------------------------------------
extern "C" void kernel_launch(void* const* d_in, const int* in_sizes, int n_in,
                              void* d_out, int out_size, void* d_ws, size_t ws_size,
                              hipStream_t stream) {
    const float* all_emb = (const float*)d_in[0];
    const float* W       = (const float*)d_in[1];
    const float* b       = (const float*)d_in[2];
    const float* vals    = (const float*)d_in[3];
    const float* drop_u  = (const float*)d_in[4];   // [2, E]
    const int*   rows    = (const int*)d_in[5];
    const int*   cols    = (const int*)d_in[6];

    float* out = (float*)d_out;       // acc accumulator, then final output
    float* x1  = (float*)d_ws;        // layer-1 result, 25.6 MB

    const int n4 = N_NODES * D / 4;               // 1.6M float4s
    const int zb = (n4 + 255) / 256;              // 6250 blocks
    const int spmm_blocks = (N_EDGES + 3) / 4;    // 4 waves/block

    // x1 = 0
    zero_kernel<<<zb, 256, 0, stream>>>((float4*)x1, n4);
    // x1 = A1 @ all_emb   (layer-0 dropout)
    spmm_kernel<<<spmm_blocks, 256, 0, stream>>>(all_emb, vals, drop_u, rows, cols, x1);
    // out = fc(all_emb) + x1
    fc_add_kernel<<<N_NODES / 4, 256, 0, stream>>>(all_emb, W, b, x1, out);
    // out += A2 @ x1      (layer-1 dropout) — atomics accumulate into out
    spmm_kernel<<<spmm_blocks, 256, 0, stream>>>(x1, vals, drop_u + N_EDGES, rows, cols, out);
    // out /= 3
    scale_kernel<<<zb, 256, 0, stream>>>((float4*)out, n4);
}